// Round 1
// baseline (1366.497 us; speedup 1.0000x reference)
//
#include <hip/hip_runtime.h>
#include <hip/hip_bf16.h>
#include <math.h>

// ---------------------------------------------------------------------------
// Swin block: LN1 -> shift+window QKV attn proj +res -> LN2 -> MLP +res
// B=32 H=W=56 C=384 NH=12 HD=32 WS=7 SS=3 N=49 NW=64 M=100352 MLP_H=1536
// All GEMMs bf16 MFMA (16x16x32), fp32 accum. Residual trunk fp32 in d_out.
// Workspace layout (bytes), total 389,006,336:
//   0         wt_qkv  (1152x384 bf16)
//   884736    wt_proj (384x384 bf16)
//   1179648   wt_fc1  (1536x384 bf16)
//   2359296   wt_fc2  (384x1536 bf16)
//   3538944   biasM   (12x49x49 f32)
//   3654656   xw      (100352x384 bf16)   } reused as hidden (100352x1536 bf16)
//   80724992  qkv     (100352x1152 bf16)  }
//   311936000 attn_out(100352x384 bf16)   reused as hn
// ---------------------------------------------------------------------------

typedef short bf16x8 __attribute__((ext_vector_type(8)));
typedef float f32x4 __attribute__((ext_vector_type(4)));

#define GLOAD_LDS16(g, s)                                                      \
    __builtin_amdgcn_global_load_lds(                                          \
        (const __attribute__((address_space(1))) void*)(g),                    \
        (__attribute__((address_space(3))) void*)(s), 16, 0, 0)

// ---- weight transpose + fp32->bf16 convert: Wt[n*K+k] = W[k*Nc+n] ----------
__global__ __launch_bounds__(256) void wconv_k(const float* __restrict__ W,
                                               __hip_bfloat16* __restrict__ Wt,
                                               int K, int Nc) {
    int id = blockIdx.x * 256 + threadIdx.x;
    if (id >= K * Nc) return;
    int k = id / Nc, n = id % Nc;
    Wt[(size_t)n * K + k] = __float2bfloat16(W[id]);
}

// ---- rel-pos bias table -> biasM[h][i][j] ----------------------------------
__global__ __launch_bounds__(256) void biasm_k(const float* __restrict__ rpb,
                                               float* __restrict__ biasM) {
    int id = blockIdx.x * 256 + threadIdx.x;
    if (id >= 12 * 49 * 49) return;
    int h = id / 2401, rem = id % 2401, i = rem / 49, j = rem % 49;
    int ih = i / 7, iw = i % 7, jh = j / 7, jw = j % 7;
    int idx = (ih - jh + 6) * 13 + (iw - jw + 6);
    biasM[id] = rpb[idx * 12 + h];
}

// ---- LayerNorm. MODE 0: gather shifted+window-partitioned rows -> xw -------
// ---- MODE 1: plain image rows (x_res -> hn) --------------------------------
template <int MODE>
__global__ __launch_bounds__(256) void ln_k(const float* __restrict__ X,
                                            const float* __restrict__ w,
                                            const float* __restrict__ b,
                                            __hip_bfloat16* __restrict__ out) {
    int wv = threadIdx.x >> 6, lane = threadIdx.x & 63;
    int row = blockIdx.x * 4 + wv;  // output row
    size_t src_row;
    if (MODE == 0) {
        int wi = row / 49, t = row % 49;
        int bb = wi >> 6, wrem = wi & 63;
        int wh = wrem >> 3, ww = wrem & 7;
        int th = t / 7, tw = t % 7;
        int hi = (wh * 7 + th + 3) % 56;      // roll(-3): shifted[hs]=x[(hs+3)%56]
        int wimg = (ww * 7 + tw + 3) % 56;
        src_row = (size_t)(bb * 3136 + hi * 56 + wimg);
    } else {
        src_row = row;
    }
    const float* src = X + src_row * 384;
    float v[6];
    float s = 0.f, sq = 0.f;
#pragma unroll
    for (int i = 0; i < 6; i++) {
        v[i] = src[lane + i * 64];
        s += v[i];
        sq += v[i] * v[i];
    }
#pragma unroll
    for (int m = 32; m >= 1; m >>= 1) {
        s += __shfl_xor(s, m, 64);
        sq += __shfl_xor(sq, m, 64);
    }
    float mean = s * (1.f / 384.f);
    float var = sq * (1.f / 384.f) - mean * mean;
    float rstd = rsqrtf(var + 1e-5f);
    size_t orow = (size_t)row * 384;
#pragma unroll
    for (int i = 0; i < 6; i++) {
        int c = lane + i * 64;
        out[orow + c] = __float2bfloat16((v[i] - mean) * rstd * w[c] + b[c]);
    }
}

// ---- generic 128x128x(BK=32) bf16 MFMA GEMM, A[M,K] x Bt[N,K]^T ------------
// EPI 0: +bias -> bf16 (qkv)        EPI 1: +bias, window-reverse+unshift,
// EPI 2: +bias, GELU -> bf16 (fc1)         +residual(x) -> f32 (proj)
// EPI 3: +bias +residual -> f32 (fc2)
template <int EPI>
__global__ __launch_bounds__(256) void gemm_k(
    const __hip_bfloat16* __restrict__ A, const __hip_bfloat16* __restrict__ Bt,
    const float* __restrict__ bias, int K, int nTilesN,
    __hip_bfloat16* outb, float* outf, const float* resin) {
    __shared__ __align__(16) __hip_bfloat16 Asm[128 * 32];
    __shared__ __align__(16) __hip_bfloat16 Bsm[128 * 32];
    int bid = blockIdx.x;
    int tM = bid / nTilesN, tN = bid % nTilesN;
    size_t m0 = (size_t)tM * 128;
    int n0 = tN * 128;
    int tid = threadIdx.x, wv = tid >> 6, lane = tid & 63;
    int wr = wv >> 1, wc = wv & 1;
    int lm = lane & 15, lg = lane >> 4;

    f32x4 acc[4][4];
#pragma unroll
    for (int i = 0; i < 4; i++)
#pragma unroll
        for (int j = 0; j < 4; j++) acc[i][j] = (f32x4){0.f, 0.f, 0.f, 0.f};

    // staging geometry: chunk = 1KB = 16 rows x 32 bf16; lane covers 16B
    int c0 = wv * 2;                  // this wave stages chunks c0, c0+1 (A and B)
    int rA0 = c0 * 16 + (lane >> 2);  // row within 128-tile
    int kk = (lane & 3) * 8;          // bf16 offset within 32-wide k slice

    int nkt = K >> 5;
    for (int kt = 0; kt < nkt; kt++) {
        int k0 = kt << 5;
        GLOAD_LDS16(A + (m0 + rA0) * K + k0 + kk, &Asm[c0 * 512]);
        GLOAD_LDS16(A + (m0 + rA0 + 16) * K + k0 + kk, &Asm[(c0 + 1) * 512]);
        GLOAD_LDS16(Bt + (size_t)(n0 + rA0) * K + k0 + kk, &Bsm[c0 * 512]);
        GLOAD_LDS16(Bt + (size_t)(n0 + rA0 + 16) * K + k0 + kk, &Bsm[(c0 + 1) * 512]);
        __syncthreads();
        bf16x8 af[4], bfg[4];
#pragma unroll
        for (int i = 0; i < 4; i++)
            af[i] = *(const bf16x8*)&Asm[(wr * 64 + i * 16 + lm) * 32 + lg * 8];
#pragma unroll
        for (int j = 0; j < 4; j++)
            bfg[j] = *(const bf16x8*)&Bsm[(wc * 64 + j * 16 + lm) * 32 + lg * 8];
#pragma unroll
        for (int i = 0; i < 4; i++)
#pragma unroll
            for (int j = 0; j < 4; j++)
                acc[i][j] = __builtin_amdgcn_mfma_f32_16x16x32_bf16(
                    af[i], bfg[j], acc[i][j], 0, 0, 0);
        __syncthreads();
    }

    int ld = nTilesN * 128;
#pragma unroll
    for (int i = 0; i < 4; i++) {
#pragma unroll
        for (int r = 0; r < 4; r++) {
            int row = (int)m0 + wr * 64 + i * 16 + lg * 4 + r;
#pragma unroll
            for (int j = 0; j < 4; j++) {
                int col = n0 + wc * 64 + j * 16 + lm;
                float val = acc[i][j][r] + bias[col];
                if (EPI == 0) {
                    outb[(size_t)row * ld + col] = __float2bfloat16(val);
                } else if (EPI == 2) {
                    float g = 0.5f * val * (1.f + erff(val * 0.70710678118f));
                    outb[(size_t)row * ld + col] = __float2bfloat16(g);
                } else if (EPI == 1) {
                    // window-reverse + unshift + residual: row -> image pos
                    int wi = row / 49, t = row % 49;
                    int bb = wi >> 6, wrem = wi & 63;
                    int wh = wrem >> 3, ww = wrem & 7;
                    int th = t / 7, tw = t % 7;
                    int hi = (wh * 7 + th + 3) % 56;
                    int wimg = (ww * 7 + tw + 3) % 56;
                    size_t pos = (size_t)(bb * 3136 + hi * 56 + wimg) * 384 + col;
                    outf[pos] = resin[pos] + val;
                } else {  // EPI 3
                    size_t pos = (size_t)row * 384 + col;
                    outf[pos] = resin[pos] + val;
                }
            }
        }
    }
}

// ---- windowed attention: one block per (window, head) ----------------------
__global__ __launch_bounds__(256) void attn_k(const __hip_bfloat16* __restrict__ qkv,
                                              const float* __restrict__ biasM,
                                              __hip_bfloat16* __restrict__ out) {
    __shared__ __align__(16) __hip_bfloat16 vt[32 * 64];  // [dim][token], padded
    __shared__ __align__(16) __hip_bfloat16 P[64 * 64];   // softmax probs
    int bid = blockIdx.x;
    int wi = bid / 12, h = bid % 12;
    int tid = threadIdx.x, wv = tid >> 6, lane = tid & 63;
    int lm = lane & 15, lg = lane >> 4;
    int wrem = wi & 63, wh = wrem >> 3, ww = wrem & 7;

    // zero vt (covers token pad 49..63)
#pragma unroll
    for (int i = 0; i < 8; i++) vt[tid * 8 + i] = __float2bfloat16(0.f);
    __syncthreads();
    // stage v transposed: vt[d][t] = v[t][d]
    if (tid < 196) {
        int t = tid >> 2, d0 = (tid & 3) * 8;
        bf16x8 vv = *(const bf16x8*)(qkv + (size_t)(wi * 49 + t) * 1152 + 768 + h * 32 + d0);
#pragma unroll
        for (int i = 0; i < 8; i++) vt[(d0 + i) * 64 + t] = ((__hip_bfloat16*)&vv)[i];
    }

    // S = q @ k^T  (wave wv owns row-tile wv; frags straight from global)
    int qrow = wv * 16 + lm;
    if (qrow > 48) qrow = 48;
    bf16x8 aq = *(const bf16x8*)(qkv + (size_t)(wi * 49 + qrow) * 1152 + h * 32 + lg * 8);
    f32x4 S[4];
#pragma unroll
    for (int ct = 0; ct < 4; ct++) {
        int krow = ct * 16 + lm;
        if (krow > 48) krow = 48;
        bf16x8 bk = *(const bf16x8*)(qkv + (size_t)(wi * 49 + krow) * 1152 + 384 + h * 32 + lg * 8);
        S[ct] = __builtin_amdgcn_mfma_f32_16x16x32_bf16(aq, bk, (f32x4){0.f, 0.f, 0.f, 0.f}, 0, 0, 0);
    }

    // scale + rel-pos bias + shift mask + row softmax -> P (bf16, LDS)
    const float scale = 0.17677669529663687f;  // 32^-0.5
#pragma unroll
    for (int r = 0; r < 4; r++) {
        int irow = wv * 16 + lg * 4 + r;
        int ic = irow <= 48 ? irow : 48;
        int ith = ic / 7, itw = ic % 7;
        int ihs = wh * 7 + ith, iws = ww * 7 + itw;
        int ridi = (ihs < 49 ? 0 : (ihs < 53 ? 1 : 2)) * 3 + (iws < 49 ? 0 : (iws < 53 ? 1 : 2));
        float vals[4];
        float mx = -1e30f;
#pragma unroll
        for (int ct = 0; ct < 4; ct++) {
            int jcol = ct * 16 + lm;
            float sv;
            if (jcol < 49) {
                int jth = jcol / 7, jtw = jcol % 7;
                int jhs = wh * 7 + jth, jws = ww * 7 + jtw;
                int ridj = (jhs < 49 ? 0 : (jhs < 53 ? 1 : 2)) * 3 + (jws < 49 ? 0 : (jws < 53 ? 1 : 2));
                sv = S[ct][r] * scale + biasM[h * 2401 + ic * 49 + jcol] +
                     (ridi != ridj ? -100.f : 0.f);
            } else {
                sv = -1e30f;  // pad cols -> prob 0
            }
            vals[ct] = sv;
            mx = fmaxf(mx, sv);
        }
#pragma unroll
        for (int m = 8; m >= 1; m >>= 1) mx = fmaxf(mx, __shfl_xor(mx, m, 64));
        float sum = 0.f;
#pragma unroll
        for (int ct = 0; ct < 4; ct++) {
            vals[ct] = __expf(vals[ct] - mx);
            sum += vals[ct];
        }
#pragma unroll
        for (int m = 8; m >= 1; m >>= 1) sum += __shfl_xor(sum, m, 64);
        float inv = 1.f / sum;
#pragma unroll
        for (int ct = 0; ct < 4; ct++)
            P[irow * 64 + ct * 16 + lm] = __float2bfloat16(vals[ct] * inv);
    }
    __syncthreads();

    // O = P @ v   (K=64 = two 32-steps; N=32 = two col-tiles)
    f32x4 O[2] = {{0.f, 0.f, 0.f, 0.f}, {0.f, 0.f, 0.f, 0.f}};
#pragma unroll
    for (int ks = 0; ks < 2; ks++) {
        bf16x8 ap = *(const bf16x8*)&P[(wv * 16 + lm) * 64 + ks * 32 + lg * 8];
#pragma unroll
        for (int nt = 0; nt < 2; nt++) {
            bf16x8 bv = *(const bf16x8*)&vt[(nt * 16 + lm) * 64 + ks * 32 + lg * 8];
            O[nt] = __builtin_amdgcn_mfma_f32_16x16x32_bf16(ap, bv, O[nt], 0, 0, 0);
        }
    }
#pragma unroll
    for (int r = 0; r < 4; r++) {
        int row = wv * 16 + lg * 4 + r;
        if (row < 49) {
            size_t base = (size_t)(wi * 49 + row) * 384 + h * 32;
            out[base + lm] = __float2bfloat16(O[0][r]);
            out[base + 16 + lm] = __float2bfloat16(O[1][r]);
        }
    }
}

extern "C" void kernel_launch(void* const* d_in, const int* in_sizes, int n_in,
                              void* d_out, int out_size, void* d_ws, size_t ws_size,
                              hipStream_t stream) {
    (void)in_sizes; (void)n_in; (void)out_size; (void)ws_size;
    const float* x     = (const float*)d_in[0];
    const float* n1w   = (const float*)d_in[1];
    const float* n1b   = (const float*)d_in[2];
    const float* qkvw  = (const float*)d_in[3];
    const float* qkvb  = (const float*)d_in[4];
    const float* rpb   = (const float*)d_in[5];
    const float* projw = (const float*)d_in[6];
    const float* projb = (const float*)d_in[7];
    const float* n2w   = (const float*)d_in[8];
    const float* n2b   = (const float*)d_in[9];
    const float* fc1w  = (const float*)d_in[10];
    const float* fc1b  = (const float*)d_in[11];
    const float* fc2w  = (const float*)d_in[12];
    const float* fc2b  = (const float*)d_in[13];
    float* out = (float*)d_out;

    char* ws = (char*)d_ws;
    __hip_bfloat16* wt_qkv  = (__hip_bfloat16*)(ws + 0);
    __hip_bfloat16* wt_proj = (__hip_bfloat16*)(ws + 884736);
    __hip_bfloat16* wt_fc1  = (__hip_bfloat16*)(ws + 1179648);
    __hip_bfloat16* wt_fc2  = (__hip_bfloat16*)(ws + 2359296);
    float*          biasM   = (float*)(ws + 3538944);
    __hip_bfloat16* xw      = (__hip_bfloat16*)(ws + 3654656);
    __hip_bfloat16* qkv     = (__hip_bfloat16*)(ws + 80724992);
    __hip_bfloat16* attn_o  = (__hip_bfloat16*)(ws + 311936000);
    __hip_bfloat16* hidden  = xw;      // reuse xw+qkv region (308 MB)
    __hip_bfloat16* hn      = attn_o;  // reuse attn_out region

    wconv_k<<<(384 * 1152 + 255) / 256, 256, 0, stream>>>(qkvw, wt_qkv, 384, 1152);
    wconv_k<<<(384 * 384 + 255) / 256, 256, 0, stream>>>(projw, wt_proj, 384, 384);
    wconv_k<<<(384 * 1536 + 255) / 256, 256, 0, stream>>>(fc1w, wt_fc1, 384, 1536);
    wconv_k<<<(1536 * 384 + 255) / 256, 256, 0, stream>>>(fc2w, wt_fc2, 1536, 384);
    biasm_k<<<(12 * 49 * 49 + 255) / 256, 256, 0, stream>>>(rpb, biasM);

    // LN1 + cyclic shift + window partition
    ln_k<0><<<25088, 256, 0, stream>>>(x, n1w, n1b, xw);
    // QKV projection
    gemm_k<0><<<784 * 9, 256, 0, stream>>>(xw, wt_qkv, qkvb, 384, 9, qkv, nullptr, nullptr);
    // windowed attention
    attn_k<<<2048 * 12, 256, 0, stream>>>(qkv, biasM, attn_o);
    // proj + window reverse + unshift + residual -> x_res (in d_out, fp32)
    gemm_k<1><<<784 * 3, 256, 0, stream>>>(attn_o, wt_proj, projb, 384, 3, nullptr, out, x);
    // LN2
    ln_k<1><<<25088, 256, 0, stream>>>(out, n2w, n2b, hn);
    // fc1 + GELU
    gemm_k<2><<<784 * 12, 256, 0, stream>>>(hn, wt_fc1, fc1b, 384, 12, hidden, nullptr, nullptr);
    // fc2 + residual -> d_out
    gemm_k<3><<<784 * 3, 256, 0, stream>>>(hidden, wt_fc2, fc2b, 1536, 3, nullptr, out, out);
}

// Round 2
// 1329.286 us; speedup vs baseline: 1.0280x; 1.0280x over previous
//
#include <hip/hip_runtime.h>
#include <hip/hip_bf16.h>
#include <math.h>

// ---------------------------------------------------------------------------
// Swin block: LN1 -> shift+window QKV attn proj +res -> LN2 -> MLP +res
// B=32 H=W=56 C=384 NH=12 HD=32 WS=7 SS=3 N=49 NW=64 M=100352 MLP_H=1536
// GEMMs: bf16 MFMA 16x16x32, 128x128 tile, BK=32, DOUBLE-BUFFERED single-
// barrier K-loop (round 2: fixes latency exposure seen in rocprof round 1).
// Workspace layout (bytes):
//   0         wt_qkv  (1152x384 bf16)
//   884736    wt_proj (384x384 bf16)
//   1179648   wt_fc1  (1536x384 bf16)
//   2359296   wt_fc2  (384x1536 bf16)
//   3538944   biasM   (12x49x49 f32)
//   3654656   xw      (100352x384 bf16)   } reused as hidden (100352x1536 bf16)
//   80724992  qkv     (100352x1152 bf16)  }
//   311936000 attn_out(100352x384 bf16)   reused as hn
// ---------------------------------------------------------------------------

typedef short bf16x8 __attribute__((ext_vector_type(8)));
typedef float f32x4 __attribute__((ext_vector_type(4)));

#define GLOAD_LDS16(g, s)                                                      \
    __builtin_amdgcn_global_load_lds(                                          \
        (const __attribute__((address_space(1))) void*)(g),                    \
        (__attribute__((address_space(3))) void*)(s), 16, 0, 0)

// ---- merged prep: 4 weight transposes (f32->bf16) + rel-pos bias matrix ----
__global__ __launch_bounds__(256) void prep_k(
    const float* __restrict__ qkvw, const float* __restrict__ projw,
    const float* __restrict__ fc1w, const float* __restrict__ fc2w,
    const float* __restrict__ rpb,
    __hip_bfloat16* __restrict__ wt_qkv, __hip_bfloat16* __restrict__ wt_proj,
    __hip_bfloat16* __restrict__ wt_fc1, __hip_bfloat16* __restrict__ wt_fc2,
    float* __restrict__ biasM) {
    int id = blockIdx.x * 256 + threadIdx.x;
    if (id < 442368) {  // qkv_w (384x1152)
        int k = id / 1152, n = id % 1152;
        wt_qkv[(size_t)n * 384 + k] = __float2bfloat16(qkvw[id]);
        return;
    }
    id -= 442368;
    if (id < 147456) {  // proj_w (384x384)
        int k = id / 384, n = id % 384;
        wt_proj[(size_t)n * 384 + k] = __float2bfloat16(projw[id]);
        return;
    }
    id -= 147456;
    if (id < 589824) {  // fc1_w (384x1536)
        int k = id / 1536, n = id % 1536;
        wt_fc1[(size_t)n * 384 + k] = __float2bfloat16(fc1w[id]);
        return;
    }
    id -= 589824;
    if (id < 589824) {  // fc2_w (1536x384)
        int k = id / 384, n = id % 384;
        wt_fc2[(size_t)n * 1536 + k] = __float2bfloat16(fc2w[id]);
        return;
    }
    id -= 589824;
    if (id < 28812) {  // biasM[h][i][j]
        int h = id / 2401, rem = id % 2401, i = rem / 49, j = rem % 49;
        int ih = i / 7, iw = i % 7, jh = j / 7, jw = j % 7;
        int idx = (ih - jh + 6) * 13 + (iw - jw + 6);
        biasM[id] = rpb[idx * 12 + h];
    }
}

// ---- LayerNorm. MODE 0: gather shifted+window-partitioned rows -> xw -------
// ---- MODE 1: plain image rows (x_res -> hn) --------------------------------
template <int MODE>
__global__ __launch_bounds__(256) void ln_k(const float* __restrict__ X,
                                            const float* __restrict__ w,
                                            const float* __restrict__ b,
                                            __hip_bfloat16* __restrict__ out) {
    int wv = threadIdx.x >> 6, lane = threadIdx.x & 63;
    int row = blockIdx.x * 4 + wv;  // output row
    size_t src_row;
    if (MODE == 0) {
        int wi = row / 49, t = row % 49;
        int bb = wi >> 6, wrem = wi & 63;
        int wh = wrem >> 3, ww = wrem & 7;
        int th = t / 7, tw = t % 7;
        int hi = (wh * 7 + th + 3) % 56;      // roll(-3): shifted[hs]=x[(hs+3)%56]
        int wimg = (ww * 7 + tw + 3) % 56;
        src_row = (size_t)(bb * 3136 + hi * 56 + wimg);
    } else {
        src_row = row;
    }
    const float* src = X + src_row * 384;
    float v[6];
    float s = 0.f, sq = 0.f;
#pragma unroll
    for (int i = 0; i < 6; i++) {
        v[i] = src[lane + i * 64];
        s += v[i];
        sq += v[i] * v[i];
    }
#pragma unroll
    for (int m = 32; m >= 1; m >>= 1) {
        s += __shfl_xor(s, m, 64);
        sq += __shfl_xor(sq, m, 64);
    }
    float mean = s * (1.f / 384.f);
    float var = sq * (1.f / 384.f) - mean * mean;
    float rstd = rsqrtf(var + 1e-5f);
    size_t orow = (size_t)row * 384;
#pragma unroll
    for (int i = 0; i < 6; i++) {
        int c = lane + i * 64;
        out[orow + c] = __float2bfloat16((v[i] - mean) * rstd * w[c] + b[c]);
    }
}

// ---- 128x128x(BK=32) bf16 MFMA GEMM, A[M,K] x Bt[N,K]^T --------------------
// Double-buffered LDS, single barrier per K-step: stage k+1 async into buf^1
// while computing buf. Barrier's vmcnt(0) drain = pipeline depth 1.
// EPI 0: +bias -> bf16 (qkv)        EPI 1: +bias, window-reverse+unshift,
// EPI 2: +bias, GELU -> bf16 (fc1)         +residual(x) -> f32 (proj)
// EPI 3: +bias +residual -> f32 (fc2)
template <int EPI>
__global__ __launch_bounds__(256) void gemm_k(
    const __hip_bfloat16* __restrict__ A, const __hip_bfloat16* __restrict__ Bt,
    const float* __restrict__ bias, int K, int nTilesN,
    __hip_bfloat16* outb, float* outf, const float* resin) {
    __shared__ __align__(16) __hip_bfloat16 Asm[2][128 * 32];
    __shared__ __align__(16) __hip_bfloat16 Bsm[2][128 * 32];
    int bid = blockIdx.x;
    int tM = bid / nTilesN, tN = bid % nTilesN;
    size_t m0 = (size_t)tM * 128;
    int n0 = tN * 128;
    int tid = threadIdx.x, wv = tid >> 6, lane = tid & 63;
    int wr = wv >> 1, wc = wv & 1;
    int lm = lane & 15, lg = lane >> 4;

    f32x4 acc[4][4];
#pragma unroll
    for (int i = 0; i < 4; i++)
#pragma unroll
        for (int j = 0; j < 4; j++) acc[i][j] = (f32x4){0.f, 0.f, 0.f, 0.f};

    // staging geometry: chunk = 1KB = 16 rows x 32 bf16; lane covers 16B
    int c0 = wv * 2;                  // this wave stages chunks c0, c0+1 (A and B)
    int rA0 = c0 * 16 + (lane >> 2);  // row within 128-tile
    int kk = (lane & 3) * 8;          // bf16 offset within 32-wide k slice
    const __hip_bfloat16* Ap = A + (m0 + rA0) * K + kk;
    const __hip_bfloat16* Bp = Bt + (size_t)(n0 + rA0) * K + kk;

    int nkt = K >> 5;
    // prologue: stage tile 0 into buf 0
    {
        GLOAD_LDS16(Ap, &Asm[0][c0 * 512]);
        GLOAD_LDS16(Ap + (size_t)16 * K, &Asm[0][(c0 + 1) * 512]);
        GLOAD_LDS16(Bp, &Bsm[0][c0 * 512]);
        GLOAD_LDS16(Bp + (size_t)16 * K, &Bsm[0][(c0 + 1) * 512]);
    }
    for (int kt = 0; kt < nkt; kt++) {
        int cur = kt & 1;
        // barrier: (a) drains vmcnt(0) -> buf[cur] staging complete;
        //          (b) all waves' ds_reads of buf[cur^1] retired -> safe to overwrite
        __syncthreads();
        if (kt + 1 < nkt) {
            int k0 = (kt + 1) << 5;
            GLOAD_LDS16(Ap + k0, &Asm[cur ^ 1][c0 * 512]);
            GLOAD_LDS16(Ap + (size_t)16 * K + k0, &Asm[cur ^ 1][(c0 + 1) * 512]);
            GLOAD_LDS16(Bp + k0, &Bsm[cur ^ 1][c0 * 512]);
            GLOAD_LDS16(Bp + (size_t)16 * K + k0, &Bsm[cur ^ 1][(c0 + 1) * 512]);
        }
        bf16x8 af[4], bfg[4];
#pragma unroll
        for (int i = 0; i < 4; i++)
            af[i] = *(const bf16x8*)&Asm[cur][(wr * 64 + i * 16 + lm) * 32 + lg * 8];
#pragma unroll
        for (int j = 0; j < 4; j++)
            bfg[j] = *(const bf16x8*)&Bsm[cur][(wc * 64 + j * 16 + lm) * 32 + lg * 8];
#pragma unroll
        for (int i = 0; i < 4; i++)
#pragma unroll
            for (int j = 0; j < 4; j++)
                acc[i][j] = __builtin_amdgcn_mfma_f32_16x16x32_bf16(
                    af[i], bfg[j], acc[i][j], 0, 0, 0);
    }

    int ld = nTilesN * 128;
#pragma unroll
    for (int i = 0; i < 4; i++) {
#pragma unroll
        for (int r = 0; r < 4; r++) {
            int row = (int)m0 + wr * 64 + i * 16 + lg * 4 + r;
#pragma unroll
            for (int j = 0; j < 4; j++) {
                int col = n0 + wc * 64 + j * 16 + lm;
                float val = acc[i][j][r] + bias[col];
                if (EPI == 0) {
                    outb[(size_t)row * ld + col] = __float2bfloat16(val);
                } else if (EPI == 2) {
                    float g = 0.5f * val * (1.f + erff(val * 0.70710678118f));
                    outb[(size_t)row * ld + col] = __float2bfloat16(g);
                } else if (EPI == 1) {
                    // window-reverse + unshift + residual: row -> image pos
                    int wi = row / 49, t = row % 49;
                    int bb = wi >> 6, wrem = wi & 63;
                    int wh = wrem >> 3, ww = wrem & 7;
                    int th = t / 7, tw = t % 7;
                    int hi = (wh * 7 + th + 3) % 56;
                    int wimg = (ww * 7 + tw + 3) % 56;
                    size_t pos = (size_t)(bb * 3136 + hi * 56 + wimg) * 384 + col;
                    outf[pos] = resin[pos] + val;
                } else {  // EPI 3
                    size_t pos = (size_t)row * 384 + col;
                    outf[pos] = resin[pos] + val;
                }
            }
        }
    }
}

// ---- windowed attention: one block per (window, head) ----------------------
__global__ __launch_bounds__(256) void attn_k(const __hip_bfloat16* __restrict__ qkv,
                                              const float* __restrict__ biasM,
                                              __hip_bfloat16* __restrict__ out) {
    __shared__ __align__(16) __hip_bfloat16 vt[32 * 64];  // [dim][token]
    __shared__ __align__(16) __hip_bfloat16 P[64 * 64];   // softmax probs
    int bid = blockIdx.x;
    int wi = bid / 12, h = bid % 12;
    int tid = threadIdx.x, wv = tid >> 6, lane = tid & 63;
    int lm = lane & 15, lg = lane >> 4;
    int wrem = wi & 63, wh = wrem >> 3, ww = wrem & 7;

    // zero vt (covers token pad 49..63)
#pragma unroll
    for (int i = 0; i < 8; i++) vt[tid * 8 + i] = __float2bfloat16(0.f);
    __syncthreads();
    // stage v transposed: vt[d][t] = v[t][d]
    if (tid < 196) {
        int t = tid >> 2, d0 = (tid & 3) * 8;
        bf16x8 vv = *(const bf16x8*)(qkv + (size_t)(wi * 49 + t) * 1152 + 768 + h * 32 + d0);
#pragma unroll
        for (int i = 0; i < 8; i++) vt[(d0 + i) * 64 + t] = ((__hip_bfloat16*)&vv)[i];
    }

    // S = q @ k^T  (wave wv owns row-tile wv; frags straight from global)
    int qrow = wv * 16 + lm;
    if (qrow > 48) qrow = 48;
    bf16x8 aq = *(const bf16x8*)(qkv + (size_t)(wi * 49 + qrow) * 1152 + h * 32 + lg * 8);
    f32x4 S[4];
#pragma unroll
    for (int ct = 0; ct < 4; ct++) {
        int krow = ct * 16 + lm;
        if (krow > 48) krow = 48;
        bf16x8 bk = *(const bf16x8*)(qkv + (size_t)(wi * 49 + krow) * 1152 + 384 + h * 32 + lg * 8);
        S[ct] = __builtin_amdgcn_mfma_f32_16x16x32_bf16(aq, bk, (f32x4){0.f, 0.f, 0.f, 0.f}, 0, 0, 0);
    }

    // scale + rel-pos bias + shift mask + row softmax -> P (bf16, LDS)
    const float scale = 0.17677669529663687f;  // 32^-0.5
#pragma unroll
    for (int r = 0; r < 4; r++) {
        int irow = wv * 16 + lg * 4 + r;
        int ic = irow <= 48 ? irow : 48;
        int ith = ic / 7, itw = ic % 7;
        int ihs = wh * 7 + ith, iws = ww * 7 + itw;
        int ridi = (ihs < 49 ? 0 : (ihs < 53 ? 1 : 2)) * 3 + (iws < 49 ? 0 : (iws < 53 ? 1 : 2));
        float vals[4];
        float mx = -1e30f;
#pragma unroll
        for (int ct = 0; ct < 4; ct++) {
            int jcol = ct * 16 + lm;
            float sv;
            if (jcol < 49) {
                int jth = jcol / 7, jtw = jcol % 7;
                int jhs = wh * 7 + jth, jws = ww * 7 + jtw;
                int ridj = (jhs < 49 ? 0 : (jhs < 53 ? 1 : 2)) * 3 + (jws < 49 ? 0 : (jws < 53 ? 1 : 2));
                sv = S[ct][r] * scale + biasM[h * 2401 + ic * 49 + jcol] +
                     (ridi != ridj ? -100.f : 0.f);
            } else {
                sv = -1e30f;  // pad cols -> prob 0
            }
            vals[ct] = sv;
            mx = fmaxf(mx, sv);
        }
#pragma unroll
        for (int m = 8; m >= 1; m >>= 1) mx = fmaxf(mx, __shfl_xor(mx, m, 64));
        float sum = 0.f;
#pragma unroll
        for (int ct = 0; ct < 4; ct++) {
            vals[ct] = __expf(vals[ct] - mx);
            sum += vals[ct];
        }
#pragma unroll
        for (int m = 8; m >= 1; m >>= 1) sum += __shfl_xor(sum, m, 64);
        float inv = 1.f / sum;
#pragma unroll
        for (int ct = 0; ct < 4; ct++)
            P[irow * 64 + ct * 16 + lm] = __float2bfloat16(vals[ct] * inv);
    }
    __syncthreads();

    // O = P @ v   (K=64 = two 32-steps; N=32 = two col-tiles)
    f32x4 O[2] = {{0.f, 0.f, 0.f, 0.f}, {0.f, 0.f, 0.f, 0.f}};
#pragma unroll
    for (int ks = 0; ks < 2; ks++) {
        bf16x8 ap = *(const bf16x8*)&P[(wv * 16 + lm) * 64 + ks * 32 + lg * 8];
#pragma unroll
        for (int nt = 0; nt < 2; nt++) {
            bf16x8 bv = *(const bf16x8*)&vt[(nt * 16 + lm) * 64 + ks * 32 + lg * 8];
            O[nt] = __builtin_amdgcn_mfma_f32_16x16x32_bf16(ap, bv, O[nt], 0, 0, 0);
        }
    }
#pragma unroll
    for (int r = 0; r < 4; r++) {
        int row = wv * 16 + lg * 4 + r;
        if (row < 49) {
            size_t base = (size_t)(wi * 49 + row) * 384 + h * 32;
            out[base + lm] = __float2bfloat16(O[0][r]);
            out[base + 16 + lm] = __float2bfloat16(O[1][r]);
        }
    }
}

extern "C" void kernel_launch(void* const* d_in, const int* in_sizes, int n_in,
                              void* d_out, int out_size, void* d_ws, size_t ws_size,
                              hipStream_t stream) {
    (void)in_sizes; (void)n_in; (void)out_size; (void)ws_size;
    const float* x     = (const float*)d_in[0];
    const float* n1w   = (const float*)d_in[1];
    const float* n1b   = (const float*)d_in[2];
    const float* qkvw  = (const float*)d_in[3];
    const float* qkvb  = (const float*)d_in[4];
    const float* rpb   = (const float*)d_in[5];
    const float* projw = (const float*)d_in[6];
    const float* projb = (const float*)d_in[7];
    const float* n2w   = (const float*)d_in[8];
    const float* n2b   = (const float*)d_in[9];
    const float* fc1w  = (const float*)d_in[10];
    const float* fc1b  = (const float*)d_in[11];
    const float* fc2w  = (const float*)d_in[12];
    const float* fc2b  = (const float*)d_in[13];
    float* out = (float*)d_out;

    char* ws = (char*)d_ws;
    __hip_bfloat16* wt_qkv  = (__hip_bfloat16*)(ws + 0);
    __hip_bfloat16* wt_proj = (__hip_bfloat16*)(ws + 884736);
    __hip_bfloat16* wt_fc1  = (__hip_bfloat16*)(ws + 1179648);
    __hip_bfloat16* wt_fc2  = (__hip_bfloat16*)(ws + 2359296);
    float*          biasM   = (float*)(ws + 3538944);
    __hip_bfloat16* xw      = (__hip_bfloat16*)(ws + 3654656);
    __hip_bfloat16* qkv     = (__hip_bfloat16*)(ws + 80724992);
    __hip_bfloat16* attn_o  = (__hip_bfloat16*)(ws + 311936000);
    __hip_bfloat16* hidden  = xw;      // reuse xw+qkv region (308 MB)
    __hip_bfloat16* hn      = attn_o;  // reuse attn_out region

    // merged weight-convert + bias-matrix prep (1,798,284 elements)
    prep_k<<<7025, 256, 0, stream>>>(qkvw, projw, fc1w, fc2w, rpb,
                                     wt_qkv, wt_proj, wt_fc1, wt_fc2, biasM);

    // LN1 + cyclic shift + window partition
    ln_k<0><<<25088, 256, 0, stream>>>(x, n1w, n1b, xw);
    // QKV projection
    gemm_k<0><<<784 * 9, 256, 0, stream>>>(xw, wt_qkv, qkvb, 384, 9, qkv, nullptr, nullptr);
    // windowed attention
    attn_k<<<2048 * 12, 256, 0, stream>>>(qkv, biasM, attn_o);
    // proj + window reverse + unshift + residual -> x_res (in d_out, fp32)
    gemm_k<1><<<784 * 3, 256, 0, stream>>>(attn_o, wt_proj, projb, 384, 3, nullptr, out, x);
    // LN2
    ln_k<1><<<25088, 256, 0, stream>>>(out, n2w, n2b, hn);
    // fc1 + GELU
    gemm_k<2><<<784 * 12, 256, 0, stream>>>(hn, wt_fc1, fc1b, 384, 12, hidden, nullptr, nullptr);
    // fc2 + residual -> d_out
    gemm_k<3><<<784 * 3, 256, 0, stream>>>(hidden, wt_fc2, fc2b, 1536, 3, nullptr, out, out);
}